// Round 1
// baseline (408.112 us; speedup 1.0000x reference)
//
#include <hip/hip_runtime.h>

#define NLAYERS 6
#define XROW 150528   // 3*224*224
#define BATCH 512     // fixed by problem spec

typedef float v2f __attribute__((ext_vector_type(2)));

// ---------------------------------------------------------------------------
// 12-qubit state-vector sim, one block (8 waves, 512 threads) per batch elem.
// 8 amplitudes per lane (3 local bits L2..L0), 6 lane bits, 3 wave bits.
// Four phases, each hosting 3 consecutive wires locally; the phase mappings
// are a bit-rotation group so ONE remap permutation serves all transitions:
//   new l = old_lane>>3 ; new lane = ((old_lane&7)<<3)|old_wv ; new wv = old l
// Phase p: local L2,L1,L0 = wires 3p,3p+1,3p+2.
//   P0: lane N5..N0 = wires 3..8,  wv = wires 9,10,11
//   P1: lane = wires 6..11, wv = wires 0,1,2   (ctrl wire2 = W0)
//   P2: lane = wires 9,10,11,0,1,2, wv = 3,4,5 (ctrl wire5 = W0)
//   P3: lane = wires 0..5, wv = 6,7,8          (ctrl wire8 = W0)
// Ring CNOTs: 2 per phase free (local renames); boundary CNOT (3p-1 -> 3p)
// is a wave-uniform select (ctrl always W0); CNOT(11->0) folds into the
// P3->P0 remap (l ^= (wv&1)<<2) or the final measurement sign.
// LDS slot: (l<<9)|(lane<<3)|(wv ^ ((lane>>1)&7)) -> 4-way (b64 floor) on
// both write and read sides. Double-buffered: ONE barrier per remap.
//
// R1 PROBE: grid hard-coded to BATCH=512 (out_size is suspected to be a BYTE
// count -> previous grid was 2048 blocks = 4x redundant work + OOB x reads).
// qnn_kernel launched TWICE (idempotent) so dur_us = overhead + 2*t_kernel,
// which disambiguates t_kernel from the harness poison-fill floor.
// ---------------------------------------------------------------------------

__global__ void qnn_prep(const float* __restrict__ w, float* __restrict__ coef) {
    const int g = threadIdx.x;
    if (g < NLAYERS * 12) {
        const float phi = w[g*3+0], th = w[g*3+1], om = w[g*3+2];
        const float ct = cosf(0.5f*th), st = sinf(0.5f*th);
        const float sp = 0.5f*(phi+om), dm = 0.5f*(phi-om);
        const float csp = cosf(sp), ssp = sinf(sp);
        const float cdm = cosf(dm), sdm = sinf(dm);
        float* c = coef + g*8;
        c[0] =  csp*ct; c[1] = -ssp*ct;   // a = e^{-i(phi+om)/2} ct
        c[2] = -cdm*st; c[3] = -sdm*st;   // b = -e^{+i(phi-om)/2} st
        c[4] =  cdm*st; c[5] = -sdm*st;   // c = e^{-i(phi-om)/2} st
        c[6] =  csp*ct; c[7] =  ssp*ct;   // d = e^{+i(phi+om)/2} ct
    }
}

__device__ __forceinline__ v2f cfma(float s, v2f a, v2f c) {
    v2f sv = {s, s};
    return __builtin_elementwise_fma(sv, a, c);
}

template<int BP>
__device__ __forceinline__ void rot_local(v2f (&v)[8], const float* __restrict__ cf) {
    const float ar = cf[0], ai = cf[1], br = cf[2], bi = cf[3];
    const float cr = cf[4], ci = cf[5], dr = cf[6], di = cf[7];
    #pragma unroll
    for (int l0 = 0; l0 < 8; ++l0) {
        if (!(l0 & (1 << BP))) {
            const int l1 = l0 | (1 << BP);
            const v2f u0 = v[l0], u1 = v[l1];
            const v2f t0 = {-u0.y, u0.x};    // i*u0
            const v2f t1 = {-u1.y, u1.x};    // i*u1
            const v2f sar = {ar, ar}, scr = {cr, cr};
            v[l0] = cfma(bi, t1, cfma(br, u1, cfma(ai, t0, sar * u0)));
            v[l1] = cfma(di, t1, cfma(dr, u1, cfma(ci, t0, scr * u0)));
        }
    }
}

#define SWAP_AMP(A,B) { v2f t_ = v[A]; v[A] = v[B]; v[B] = t_; }
// CN(L2->L1): swap 4<->6, 5<->7 ; CN(L1->L0): swap 2<->3, 6<->7
#define RING_CNOTS_LOCAL() \
    SWAP_AMP(4,6) SWAP_AMP(5,7) SWAP_AMP(2,3) SWAP_AMP(6,7)

__global__ __launch_bounds__(512, 4) void qnn_kernel(
    const float* __restrict__ x,      // (512, 150528): only first 12 per row
    const float* __restrict__ coef,   // (72, 8) from qnn_prep
    const float* __restrict__ bias,   // scalar
    float* __restrict__ out)          // (512)
{
    __shared__ v2f st[2][4096];       // 64 KB double-buffered remap staging
    __shared__ float partial[8];

    const int tid  = threadIdx.x;     // 0..511
    const int lane = tid & 63;
    const int wv   = tid >> 6;        // 0..7
    const int b    = blockIdx.x;

    v2f v[8];
    int pb = 0;

    // hoisted remap address pieces
    const int wbase = (lane << 3) | (wv ^ ((lane >> 1) & 7));  // write: | (l<<9)
    const int rbase = wv << 9;                                  // old_l = new wv
    const int u     = lane >> 3;
    const int w7    = lane & 7;

    // ---- AngleEmbedding RX product state, built directly in P0 mapping ----
    const float* xb = x + (size_t)b * XROW;
    float fc[12], fs[12];
    #pragma unroll
    for (int j = 0; j < 12; ++j) {
        const float h = xb[j] * 0.5f;
        fc[j] = __cosf(h);
        fs[j] = __sinf(h);
    }
    // wires 3..8 on lane bits 5..0; wires 9,10,11 on wv bits 2,1,0
    float pr = 1.f, pi_ = 0.f;
    #pragma unroll
    for (int j = 3; j < 12; ++j) {
        const int bit = (j < 9) ? ((lane >> (8 - j)) & 1)
                                : ((wv >> (11 - j)) & 1);
        const float nr = bit ? (pi_ * fs[j]) : (pr * fc[j]);
        const float ni = bit ? (-pr * fs[j]) : (pi_ * fc[j]);
        pr = nr; pi_ = ni;
    }
    // wires 0,1,2 on local bits 2,1,0 (wire j on bit 2-j), doubling
    v[0] = (v2f){pr, pi_};
    #pragma unroll
    for (int bb = 0; bb < 3; ++bb) {
        const int wire = 2 - bb;
        const float cc = fc[wire], ss = fs[wire];
        const int m = 1 << bb;
        #pragma unroll
        for (int l = 0; l < 4; ++l) {
            if (l < m) {
                const float r = v[l].x, q = v[l].y;
                v[l + m] = (v2f){q * ss, -r * ss};
                v[l]     = (v2f){r * cc,  q * cc};
            }
        }
    }

    // ---- layers ----
    for (int layer = 0; layer < NLAYERS; ++layer) {
        const float* cl = coef + layer * 96;

        #pragma unroll
        for (int p = 0; p < 4; ++p) {
            // remap into phase p (skip for very first phase of layer 0)
            if (layer || p) {
                const int fold = (p == 0) ? ((wv & 1) << 2) : 0;  // CN(11->0)
                v2f* S = st[pb];
                #pragma unroll
                for (int l = 0; l < 8; ++l)
                    S[(l << 9) | wbase] = v[l];
                __syncthreads();
                #pragma unroll
                for (int l = 0; l < 8; ++l) {
                    const int ol = ((l ^ fold) << 3) | u;          // old_lane
                    v[l] = S[rbase | (ol << 3) | (w7 ^ ((ol >> 1) & 7))];
                }
                pb ^= 1;
            }

            // Rot gates: wire 3p on L2, 3p+1 on L1, 3p+2 on L0
            rot_local<2>(v, cl + (3 * p + 0) * 8);
            rot_local<1>(v, cl + (3 * p + 1) * 8);
            rot_local<0>(v, cl + (3 * p + 2) * 8);

            // boundary CNOT (3p-1 -> 3p): ctrl = W0, tgt = L2  (phases 1..3)
            if (p) {
                const bool sel = wv & 1;
                #pragma unroll
                for (int l = 0; l < 4; ++l) {
                    const v2f a0 = v[l], a1 = v[l + 4];
                    v[l]     = sel ? a1 : a0;
                    v[l + 4] = sel ? a0 : a1;
                }
            }
            // local ring CNOTs (3p->3p+1), (3p+1->3p+2)
            RING_CNOTS_LOCAL();
        }
        // CN(11->0) folded into next P3->P0 remap / final measurement sign
    }

    // ---- <Z_0> with folded CNOT(11->0): sign = b11 ^ b0 = lane[5] ^ l[0] ----
    float acc = 0.f;
    #pragma unroll
    for (int l = 0; l < 8; ++l) {
        const float p = v[l].x * v[l].x + v[l].y * v[l].y;
        acc += ((((lane >> 5) ^ l) & 1) ? -p : p);
    }
    #pragma unroll
    for (int off = 32; off > 0; off >>= 1)
        acc += __shfl_down(acc, off, 64);
    if (lane == 0) partial[wv] = acc;
    __syncthreads();
    if (tid == 0) {
        float s = 0.f;
        #pragma unroll
        for (int i = 0; i < 8; ++i) s += partial[i];
        out[b] = s + bias[0];
    }
}

extern "C" void kernel_launch(void* const* d_in, const int* in_sizes, int n_in,
                              void* d_out, int out_size, void* d_ws, size_t ws_size,
                              hipStream_t stream) {
    (void)in_sizes; (void)n_in; (void)out_size; (void)ws_size;
    const float* x    = (const float*)d_in[0];
    const float* wts  = (const float*)d_in[1];
    const float* bias = (const float*)d_in[2];
    float* out  = (float*)d_out;
    float* coef = (float*)d_ws;       // 72*8 floats = 2304 B
    qnn_prep<<<1, 128, 0, stream>>>(wts, coef);
    // R1 probe: hard-coded grid=BATCH (out_size unit suspect); double launch
    // is idempotent and makes dur_us = overhead + 2*t_kernel.
    qnn_kernel<<<BATCH, 512, 0, stream>>>(x, coef, bias, out);
    qnn_kernel<<<BATCH, 512, 0, stream>>>(x, coef, bias, out);
}

// Round 3
// 368.309 us; speedup vs baseline: 1.1081x; 1.1081x over previous
//
#include <hip/hip_runtime.h>

#define NLAYERS 6
#define XROW 150528   // 3*224*224
#define BATCH 512     // fixed by problem spec

typedef float v2f __attribute__((ext_vector_type(2)));

// ---------------------------------------------------------------------------
// 12-qubit state-vector sim, one block (8 waves, 512 threads) per batch elem.
// 8 amplitudes per lane (3 local bits L2..L0), 6 lane bits, 3 wave bits.
// Four phases, each hosting 3 consecutive wires locally; the phase mappings
// are a bit-rotation group so ONE remap permutation serves all transitions:
//   new l = old_lane>>3 ; new lane = ((old_lane&7)<<3)|old_wv ; new wv = old l
// Phase p: local L2,L1,L0 = wires 3p,3p+1,3p+2.
//   P0: lane N5..N0 = wires 3..8,  wv = wires 9,10,11
//   P1: lane = wires 6..11, wv = wires 0,1,2   (ctrl wire2 = W0)
//   P2: lane = wires 9,10,11,0,1,2, wv = 3,4,5 (ctrl wire5 = W0)
//   P3: lane = wires 0..5, wv = 6,7,8          (ctrl wire8 = W0)
// Ring CNOTs: 2 per phase free (local renames); boundary CNOT (3p-1 -> 3p,
// ctrl always W0, tgt L2) is FOLDED INTO the wire-3p rot as a wave-uniform
// coefficient ROW SWAP (rot-then-swap == row-swapped-rot), selected via
// SGPR pointers (readfirstlane) so coef reads stay scalar loads.
// CNOT(11->0) folds into the P3->P0 remap (l ^= (wv&1)<<2) or the final
// measurement sign.
// LDS slot: (l<<9)|(lane<<3)|(wv ^ ((lane>>1)&7)) -> 4-way (b64 floor) on
// both write and read sides. Double-buffered: ONE barrier per remap.
//
// Measured (R0/R1 probe): t_kernel ~= 36 us; harness poison fills ~= 336 us
// fixed. This version: single launch + boundary-CNOT fold (-18x16 cndmask)
// + rot order <0><1><2> for earlier readiness after remap reads.
// (R2 was an infra failure — identical source resubmitted.)
// ---------------------------------------------------------------------------

__global__ void qnn_prep(const float* __restrict__ w, float* __restrict__ coef) {
    const int g = threadIdx.x;
    if (g < NLAYERS * 12) {
        const float phi = w[g*3+0], th = w[g*3+1], om = w[g*3+2];
        const float ct = cosf(0.5f*th), st = sinf(0.5f*th);
        const float sp = 0.5f*(phi+om), dm = 0.5f*(phi-om);
        const float csp = cosf(sp), ssp = sinf(sp);
        const float cdm = cosf(dm), sdm = sinf(dm);
        float* c = coef + g*8;
        c[0] =  csp*ct; c[1] = -ssp*ct;   // a = e^{-i(phi+om)/2} ct
        c[2] = -cdm*st; c[3] = -sdm*st;   // b = -e^{+i(phi-om)/2} st
        c[4] =  cdm*st; c[5] = -sdm*st;   // c = e^{-i(phi-om)/2} st
        c[6] =  csp*ct; c[7] =  ssp*ct;   // d = e^{+i(phi+om)/2} ct
    }
}

__device__ __forceinline__ v2f cfma(float s, v2f a, v2f c) {
    v2f sv = {s, s};
    return __builtin_elementwise_fma(sv, a, c);
}

// rot with split row pointers: r0 -> coeffs producing the tgt=0 output row,
// r1 -> coeffs producing the tgt=1 output row. Normal: r0=cf, r1=cf+4.
// Row-swapped (folded boundary CNOT, ctrl==1 waves): r0=cf+4, r1=cf.
template<int BP>
__device__ __forceinline__ void rot_local2(v2f (&v)[8],
                                           const float* __restrict__ r0,
                                           const float* __restrict__ r1) {
    const float ar = r0[0], ai = r0[1], br = r0[2], bi = r0[3];
    const float cr = r1[0], ci = r1[1], dr = r1[2], di = r1[3];
    #pragma unroll
    for (int l0 = 0; l0 < 8; ++l0) {
        if (!(l0 & (1 << BP))) {
            const int l1 = l0 | (1 << BP);
            const v2f u0 = v[l0], u1 = v[l1];
            const v2f t0 = {-u0.y, u0.x};    // i*u0
            const v2f t1 = {-u1.y, u1.x};    // i*u1
            const v2f sar = {ar, ar}, scr = {cr, cr};
            v[l0] = cfma(bi, t1, cfma(br, u1, cfma(ai, t0, sar * u0)));
            v[l1] = cfma(di, t1, cfma(dr, u1, cfma(ci, t0, scr * u0)));
        }
    }
}

template<int BP>
__device__ __forceinline__ void rot_local(v2f (&v)[8], const float* __restrict__ cf) {
    rot_local2<BP>(v, cf, cf + 4);
}

#define SWAP_AMP(A,B) { v2f t_ = v[A]; v[A] = v[B]; v[B] = t_; }
// CN(L2->L1): swap 4<->6, 5<->7 ; CN(L1->L0): swap 2<->3, 6<->7
#define RING_CNOTS_LOCAL() \
    SWAP_AMP(4,6) SWAP_AMP(5,7) SWAP_AMP(2,3) SWAP_AMP(6,7)

__global__ __launch_bounds__(512, 4) void qnn_kernel(
    const float* __restrict__ x,      // (512, 150528): only first 12 per row
    const float* __restrict__ coef,   // (72, 8) from qnn_prep
    const float* __restrict__ bias,   // scalar
    float* __restrict__ out)          // (512)
{
    __shared__ v2f st[2][4096];       // 64 KB double-buffered remap staging
    __shared__ float partial[8];

    const int tid  = threadIdx.x;     // 0..511
    const int lane = tid & 63;
    const int wv   = tid >> 6;        // 0..7
    const int b    = blockIdx.x;

    v2f v[8];
    int pb = 0;

    // hoisted remap address pieces
    const int wbase = (lane << 3) | (wv ^ ((lane >> 1) & 7));  // write: | (l<<9)
    const int rbase = wv << 9;                                  // old_l = new wv
    const int u     = lane >> 3;
    const int w7    = lane & 7;

    // wave-uniform boundary-CNOT row-swap selector (SGPR!)
    const int sel  = __builtin_amdgcn_readfirstlane(wv) & 1;
    const int off0 = sel << 2;        // 4 floats if ctrl==1
    const int off1 = off0 ^ 4;

    // ---- AngleEmbedding RX product state, built directly in P0 mapping ----
    const float* xb = x + (size_t)b * XROW;
    float fc[12], fs[12];
    #pragma unroll
    for (int j = 0; j < 12; ++j) {
        const float h = xb[j] * 0.5f;
        fc[j] = __cosf(h);
        fs[j] = __sinf(h);
    }
    // wires 3..8 on lane bits 5..0; wires 9,10,11 on wv bits 2,1,0
    float pr = 1.f, pi_ = 0.f;
    #pragma unroll
    for (int j = 3; j < 12; ++j) {
        const int bit = (j < 9) ? ((lane >> (8 - j)) & 1)
                                : ((wv >> (11 - j)) & 1);
        const float nr = bit ? (pi_ * fs[j]) : (pr * fc[j]);
        const float ni = bit ? (-pr * fs[j]) : (pi_ * fc[j]);
        pr = nr; pi_ = ni;
    }
    // wires 0,1,2 on local bits 2,1,0 (wire j on bit 2-j), doubling
    v[0] = (v2f){pr, pi_};
    #pragma unroll
    for (int bb = 0; bb < 3; ++bb) {
        const int wire = 2 - bb;
        const float cc = fc[wire], ss = fs[wire];
        const int m = 1 << bb;
        #pragma unroll
        for (int l = 0; l < 4; ++l) {
            if (l < m) {
                const float r = v[l].x, q = v[l].y;
                v[l + m] = (v2f){q * ss, -r * ss};
                v[l]     = (v2f){r * cc,  q * cc};
            }
        }
    }

    // ---- layers ----
    for (int layer = 0; layer < NLAYERS; ++layer) {
        const float* cl = coef + layer * 96;

        #pragma unroll
        for (int p = 0; p < 4; ++p) {
            // remap into phase p (skip for very first phase of layer 0)
            if (layer || p) {
                const int fold = (p == 0) ? ((wv & 1) << 2) : 0;  // CN(11->0)
                v2f* S = st[pb];
                #pragma unroll
                for (int l = 0; l < 8; ++l)
                    S[(l << 9) | wbase] = v[l];
                __syncthreads();
                #pragma unroll
                for (int l = 0; l < 8; ++l) {
                    const int ol = ((l ^ fold) << 3) | u;          // old_lane
                    v[l] = S[rbase | (ol << 3) | (w7 ^ ((ol >> 1) & 7))];
                }
                pb ^= 1;
            }

            // Rot gates: wire 3p on L2, 3p+1 on L1, 3p+2 on L0 (rots commute;
            // order <0><1><2> so the first pair is ready earliest after reads).
            rot_local<0>(v, cl + (3 * p + 2) * 8);
            rot_local<1>(v, cl + (3 * p + 1) * 8);
            const float* c2 = cl + (3 * p + 0) * 8;
            if (p) {
                // boundary CNOT (3p-1 -> 3p, ctrl=W0, tgt=L2) folded into the
                // wire-3p rot as a wave-uniform coefficient row swap.
                rot_local2<2>(v, c2 + off0, c2 + off1);
            } else {
                rot_local<2>(v, c2);
            }
            // local ring CNOTs (3p->3p+1), (3p+1->3p+2)
            RING_CNOTS_LOCAL();
        }
        // CN(11->0) folded into next P3->P0 remap / final measurement sign
    }

    // ---- <Z_0> with folded CNOT(11->0): sign = b11 ^ b0 = lane[5] ^ l[0] ----
    float acc = 0.f;
    #pragma unroll
    for (int l = 0; l < 8; ++l) {
        const float p = v[l].x * v[l].x + v[l].y * v[l].y;
        acc += ((((lane >> 5) ^ l) & 1) ? -p : p);
    }
    #pragma unroll
    for (int off = 32; off > 0; off >>= 1)
        acc += __shfl_down(acc, off, 64);
    if (lane == 0) partial[wv] = acc;
    __syncthreads();
    if (tid == 0) {
        float s = 0.f;
        #pragma unroll
        for (int i = 0; i < 8; ++i) s += partial[i];
        out[b] = s + bias[0];
    }
}

extern "C" void kernel_launch(void* const* d_in, const int* in_sizes, int n_in,
                              void* d_out, int out_size, void* d_ws, size_t ws_size,
                              hipStream_t stream) {
    (void)in_sizes; (void)n_in; (void)out_size; (void)ws_size;
    const float* x    = (const float*)d_in[0];
    const float* wts  = (const float*)d_in[1];
    const float* bias = (const float*)d_in[2];
    float* out  = (float*)d_out;
    float* coef = (float*)d_ws;       // 72*8 floats = 2304 B
    qnn_prep<<<1, 128, 0, stream>>>(wts, coef);
    qnn_kernel<<<BATCH, 512, 0, stream>>>(x, coef, bias, out);
}